// Round 1
// baseline (776.888 us; speedup 1.0000x reference)
//
#include <hip/hip_runtime.h>

#define NPG    50
#define HF     128
#define FDIM   64
#define NGRAPH 2048
#define NNODES 102400
#define ERAND  819200
#define EPG    400
#define EPGT   450   // 400 random + 50 self loops per graph

__device__ __forceinline__ float leaky(float x, float s) { return x >= 0.f ? x : x * s; }
// order-preserving float->int key for atomicMax
__device__ __forceinline__ int fkey(float f) { int b = __float_as_int(f); return b >= 0 ? b : b ^ 0x7fffffff; }
__device__ __forceinline__ float funkey(int k) { return __int_as_float(k >= 0 ? k : k ^ 0x7fffffff); }

// out[n][j] = sum_k in[n][k] * W[k][j]; in: [NNODES,K], W: [K,128], out: [NNODES,128]
// 64 nodes per block; thread = (col j, col j+64) x 16 rows.
template <int K>
__global__ __launch_bounds__(256) void gemm_kernel(const float* __restrict__ in,
                                                   const float* __restrict__ Wg,
                                                   float* __restrict__ out) {
    __shared__ float in_s[64 * (K + 4)];
    const int t = threadIdx.x;
    const int nblk = blockIdx.x * 64;

    const float4* gsrc = (const float4*)(in + (size_t)nblk * K);
    for (int i = t; i < 64 * K / 4; i += 256) {
        float4 v = gsrc[i];
        int flat = i * 4;
        int n = flat / K, k = flat % K;
        *(float4*)&in_s[n * (K + 4) + k] = v;
    }
    __syncthreads();

    const int j = t & 63;
    const int n0 = (t >> 6) * 16;
    float accA[16], accB[16];
#pragma unroll
    for (int i = 0; i < 16; ++i) { accA[i] = 0.f; accB[i] = 0.f; }

    for (int k = 0; k < K; k += 4) {
        float wA[4], wB[4];
#pragma unroll
        for (int kk = 0; kk < 4; ++kk) {
            wA[kk] = Wg[(k + kk) * HF + j];
            wB[kk] = Wg[(k + kk) * HF + j + 64];
        }
#pragma unroll
        for (int i = 0; i < 16; ++i) {
            float4 h4 = *(const float4*)&in_s[(n0 + i) * (K + 4) + k];
            accA[i] = fmaf(h4.x, wA[0], accA[i]);
            accA[i] = fmaf(h4.y, wA[1], accA[i]);
            accA[i] = fmaf(h4.z, wA[2], accA[i]);
            accA[i] = fmaf(h4.w, wA[3], accA[i]);
            accB[i] = fmaf(h4.x, wB[0], accB[i]);
            accB[i] = fmaf(h4.y, wB[1], accB[i]);
            accB[i] = fmaf(h4.z, wB[2], accB[i]);
            accB[i] = fmaf(h4.w, wB[3], accB[i]);
        }
    }

    float* orow = out + (size_t)(nblk + n0) * HF;
#pragma unroll
    for (int i = 0; i < 16; ++i) {
        orow[i * HF + j] = accA[i];
        orow[i * HF + j + 64] = accB[i];
    }
}

// One block per graph: attention softmax + aggregation + residual + LayerNorm +
// leaky + head-mean + graph-mean readout (with final leaky fused).
__global__ __launch_bounds__(256) void graph_kernel(
    const float* __restrict__ feat, const float* __restrict__ res,
    const float* __restrict__ al, const float* __restrict__ ar,
    const float* __restrict__ gw, const float* __restrict__ bw,
    const int* __restrict__ src, const int* __restrict__ dst,
    float* __restrict__ hout, float* __restrict__ out,
    int layer, int write_h) {
    __shared__ float feat_s[NPG][HF + 4];
    __shared__ float rst_s[NPG][HF + 4];
    __shared__ float el_s[NPG][2], er_s[NPG][2];
    __shared__ int keymax[NPG][2];
    __shared__ float denom[NPG][2];
    __shared__ float ex_s[EPGT][2];
    __shared__ int lsld[EPGT];
    __shared__ int deg_s[NPG], off_s[NPG + 1], pos_s[NPG];
    __shared__ int eord[EPGT];
    __shared__ float mu_s[NPG], rs_s[NPG];

    const int g = blockIdx.x, t = threadIdx.x;
    const int nbase = g * NPG;

    // stage this graph's feat rows (contiguous 50*128 floats)
    const float4* fsrc = (const float4*)(feat + (size_t)nbase * HF);
    for (int i = t; i < NPG * HF / 4; i += 256) {
        int flat = i * 4;
        int n = flat >> 7, k = flat & 127;
        *(float4*)&feat_s[n][k] = fsrc[i];
    }
    // init small arrays
    for (int i = t; i < NPG * 2; i += 256) {
        (&keymax[0][0])[i] = (int)0x80000000;
        (&denom[0][0])[i] = 0.f;
    }
    for (int i = t; i < NPG; i += 256) deg_s[i] = 0;
    __syncthreads();

    // el/er per (node, head)
    if (t < NPG * 2) {
        int n = t >> 1, h = t & 1;
        float a = 0.f, b = 0.f;
        for (int f = 0; f < FDIM; ++f) {
            float fv = feat_s[n][h * FDIM + f];
            a = fmaf(fv, al[h * FDIM + f], a);
            b = fmaf(fv, ar[h * FDIM + f], b);
        }
        el_s[n][h] = a;
        er_s[n][h] = b;
    }
    __syncthreads();

    // pass A: edge scores, per-dst max, degree count
    for (int i = t; i < EPGT; i += 256) {
        int eid = (i < EPG) ? (g * EPG + i) : (ERAND + nbase + (i - EPG));
        int s = src[eid] - nbase, d = dst[eid] - nbase;
        lsld[i] = s | (d << 8);
        float e0 = leaky(el_s[s][0] + er_s[d][0], 0.2f);
        float e1 = leaky(el_s[s][1] + er_s[d][1], 0.2f);
        ex_s[i][0] = e0;
        ex_s[i][1] = e1;
        atomicMax(&keymax[d][0], fkey(e0));
        atomicMax(&keymax[d][1], fkey(e1));
        atomicAdd(&deg_s[d], 1);
    }
    __syncthreads();

    if (t == 0) {
        int acc = 0;
        for (int d = 0; d < NPG; ++d) {
            off_s[d] = acc;
            pos_s[d] = acc;
            acc += deg_s[d];
        }
        off_s[NPG] = acc;
    }
    __syncthreads();

    // pass B: exp, denom, CSR scatter by dst
    for (int i = t; i < EPGT; i += 256) {
        int d = lsld[i] >> 8;
        float m0 = funkey(keymax[d][0]), m1 = funkey(keymax[d][1]);
        float x0 = __expf(ex_s[i][0] - m0), x1 = __expf(ex_s[i][1] - m1);
        ex_s[i][0] = x0;
        ex_s[i][1] = x1;
        atomicAdd(&denom[d][0], x0);
        atomicAdd(&denom[d][1], x1);
        int slot = atomicAdd(&pos_s[d], 1);
        eord[slot] = i;
    }
    __syncthreads();

    // aggregation: rst[d][f] = (sum_in ex*feat[src]) / denom
    for (int w = t; w < NPG * HF; w += 256) {
        int d = w >> 7, f = w & 127, h = f >> 6;
        float sum = 0.f;
        int q0 = off_s[d], q1 = off_s[d + 1];
        for (int q = q0; q < q1; ++q) {
            int i = eord[q];
            int s = lsld[i] & 255;
            sum = fmaf(ex_s[i][h], feat_s[s][f], sum);
        }
        rst_s[d][f] = sum / denom[d][h];
    }
    __syncthreads();

    // residual add
    const float* rsrc = res + (size_t)nbase * HF;
    for (int w = t; w < NPG * HF; w += 256) {
        int n = w >> 7, jj = w & 127;
        rst_s[n][jj] += rsrc[w];
    }
    __syncthreads();

    // LayerNorm stats (one thread per node)
    if (t < NPG) {
        float s = 0.f;
        for (int jj = 0; jj < HF; ++jj) s += rst_s[t][jj];
        float mu = s * (1.f / HF);
        float v = 0.f;
        for (int jj = 0; jj < HF; ++jj) {
            float dd = rst_s[t][jj] - mu;
            v = fmaf(dd, dd, v);
        }
        mu_s[t] = mu;
        rs_s[t] = rsqrtf(v * (1.f / HF) + 1e-5f);
    }
    __syncthreads();

    // normalize + affine + leaky, write next-layer h
    for (int w = t; w < NPG * HF; w += 256) {
        int n = w >> 7, jj = w & 127;
        float y = (rst_s[n][jj] - mu_s[n]) * rs_s[n] * gw[jj] + bw[jj];
        y = leaky(y, 0.1f);
        rst_s[n][jj] = y;
        if (write_h) hout[(size_t)nbase * HF + w] = y;
    }
    __syncthreads();

    // readout: mean over heads, mean over nodes, final leaky
    if (t < FDIM) {
        float s = 0.f;
        for (int n = 0; n < NPG; ++n) s += rst_s[n][t] + rst_s[n][t + FDIM];
        s *= (0.5f / NPG);
        out[(size_t)g * (3 * FDIM) + layer * FDIM + t] = leaky(s, 0.1f);
    }
}

extern "C" void kernel_launch(void* const* d_in, const int* in_sizes, int n_in,
                              void* d_out, int out_size, void* d_ws, size_t ws_size,
                              hipStream_t stream) {
    const float* x   = (const float*)d_in[0];
    const float* W0  = (const float*)d_in[1];
    const float* al0 = (const float*)d_in[2];
    const float* ar0 = (const float*)d_in[3];
    const float* rW0 = (const float*)d_in[4];
    const float* g0  = (const float*)d_in[5];
    const float* b0  = (const float*)d_in[6];
    const float* W1  = (const float*)d_in[7];
    const float* al1 = (const float*)d_in[8];
    const float* ar1 = (const float*)d_in[9];
    const float* g1  = (const float*)d_in[10];
    const float* b1  = (const float*)d_in[11];
    const float* W2  = (const float*)d_in[12];
    const float* al2 = (const float*)d_in[13];
    const float* ar2 = (const float*)d_in[14];
    const float* g2  = (const float*)d_in[15];
    const float* b2  = (const float*)d_in[16];
    const int* src   = (const int*)d_in[17];
    const int* dst   = (const int*)d_in[18];
    float* out = (float*)d_out;

    float* bufA = (float*)d_ws;                    // h ping buffer [N,128]
    float* bufB = bufA + (size_t)NNODES * HF;      // h pong buffer / res0 overlay
    float* feat = bufB + (size_t)NNODES * HF;      // per-layer feat [N,128]

    // Layer 0
    gemm_kernel<64><<<NNODES / 64, 256, 0, stream>>>(x, W0, feat);
    gemm_kernel<64><<<NNODES / 64, 256, 0, stream>>>(x, rW0, bufB);   // res0 = x @ resW0
    graph_kernel<<<NGRAPH, 256, 0, stream>>>(feat, bufB, al0, ar0, g0, b0, src, dst, bufA, out, 0, 1);
    // Layer 1 (identity residual = bufA)
    gemm_kernel<128><<<NNODES / 64, 256, 0, stream>>>(bufA, W1, feat);
    graph_kernel<<<NGRAPH, 256, 0, stream>>>(feat, bufA, al1, ar1, g1, b1, src, dst, bufB, out, 1, 1);
    // Layer 2 (identity residual = bufB, no h write needed)
    gemm_kernel<128><<<NNODES / 64, 256, 0, stream>>>(bufB, W2, feat);
    graph_kernel<<<NGRAPH, 256, 0, stream>>>(feat, bufB, al2, ar2, g2, b2, src, dst, bufA, out, 2, 0);
}

// Round 2
// 639.788 us; speedup vs baseline: 1.2143x; 1.2143x over previous
//
#include <hip/hip_runtime.h>

#define NPG    50
#define HF     128
#define FDIM   64
#define NGRAPH 2048
#define NNODES 102400
#define EPG    400
#define AP     52    // padded attention-matrix stride (multiple of 4 for float4)
#define FP     132   // padded feat row stride

__device__ __forceinline__ float leaky(float x, float s) { return x >= 0.f ? x : x * s; }

// One block per graph, fully fused layer:
//   GEMM (feat = h@W [+ res = h@resW]) -> attention softmax (dense 50x50) ->
//   aggregation (dense matmul) -> residual -> LayerNorm -> leaky -> h write +
//   graph readout.
template<int K, bool RESW, bool WRITE_H>
__global__ __launch_bounds__(256, 2) void layer_kernel(
    const float* __restrict__ hin, const float* __restrict__ W,
    const float* __restrict__ Wres, const float* __restrict__ al,
    const float* __restrict__ ar, const float* __restrict__ gw,
    const float* __restrict__ bw, const int* __restrict__ src,
    const int* __restrict__ dst, float* __restrict__ hout,
    float* __restrict__ out, int layer)
{
    __shared__ float h_s[NPG * K];
    __shared__ float feat_s[NPG * FP];
    __shared__ float A_s[2 * NPG * AP];          // plane1 aliased as cnt
    __shared__ float el_s[NPG][2], er_s[NPG][2];
    __shared__ float m_s[NPG][2], rden_s[NPG][2];
    __shared__ float mu_s[NPG], rs_s[NPG];
    __shared__ float psum[2][HF];

    const int g = blockIdx.x, t = threadIdx.x;
    const int nbase = g * NPG;
    const int j = t & 127, grp = t >> 7;
    const int n0 = grp * 25;
    int* cnt = (int*)(A_s + NPG * AP);

    // stage this graph's h rows (contiguous), zero cnt
    const float4* hs4 = (const float4*)(hin + (size_t)nbase * K);
    for (int i = t; i < NPG * K / 4; i += 256) ((float4*)h_s)[i] = hs4[i];
    for (int i = t; i < NPG * AP; i += 256) cnt[i] = 0;
    __syncthreads();

    // issue edge loads early (counted later); self-loop block is structural
    int es0, ed0, es1 = 0, ed1 = 0;
    es0 = src[g * EPG + t] - nbase;
    ed0 = dst[g * EPG + t] - nbase;
    const bool has1 = (t + 256) < EPG;
    if (has1) {
        es1 = src[g * EPG + t + 256] - nbase;
        ed1 = dst[g * EPG + t + 256] - nbase;
    }

    // ---- GEMM: thread = (col j, 25 nodes of its group) ----
    float accF[25];
    float accR[RESW ? 25 : 1];
#pragma unroll
    for (int i = 0; i < 25; ++i) accF[i] = 0.f;
    if constexpr (RESW) {
#pragma unroll
        for (int i = 0; i < 25; ++i) accR[i] = 0.f;
    }
    const float* Wj = W + j;
    const float* Wrj = RESW ? (Wres + j) : W + j;
    float wf[4], wr[4];
#pragma unroll
    for (int u = 0; u < 4; ++u) {
        wf[u] = Wj[u * HF];
        if constexpr (RESW) wr[u] = Wrj[u * HF];
    }
    for (int k = 0; k < K; k += 4) {
        float nf[4] = {0.f, 0.f, 0.f, 0.f}, nr[4] = {0.f, 0.f, 0.f, 0.f};
        if (k + 4 < K) {
#pragma unroll
            for (int u = 0; u < 4; ++u) {
                nf[u] = Wj[(k + 4 + u) * HF];
                if constexpr (RESW) nr[u] = Wrj[(k + 4 + u) * HF];
            }
        }
#pragma unroll
        for (int i = 0; i < 25; ++i) {
            float4 h4 = *(const float4*)&h_s[(n0 + i) * K + k];
            float v = accF[i];
            v = fmaf(h4.x, wf[0], v);
            v = fmaf(h4.y, wf[1], v);
            v = fmaf(h4.z, wf[2], v);
            v = fmaf(h4.w, wf[3], v);
            accF[i] = v;
            if constexpr (RESW) {
                float r = accR[i];
                r = fmaf(h4.x, wr[0], r);
                r = fmaf(h4.y, wr[1], r);
                r = fmaf(h4.z, wr[2], r);
                r = fmaf(h4.w, wr[3], r);
                accR[i] = r;
            }
        }
#pragma unroll
        for (int u = 0; u < 4; ++u) {
            wf[u] = nf[u];
            if constexpr (RESW) wr[u] = nr[u];
        }
    }
#pragma unroll
    for (int i = 0; i < 25; ++i) feat_s[(n0 + i) * FP + j] = accF[i];

    // edge counts (dense 50x50, padded to 52)
    atomicAdd(&cnt[ed0 * AP + es0], 1);
    if (has1) atomicAdd(&cnt[ed1 * AP + es1], 1);
    if (t < NPG) atomicAdd(&cnt[t * AP + t], 1);   // self loops
    __syncthreads();

    // el/er per (node, head)
    if (t < 2 * NPG) {
        int n = t >> 1, h = t & 1;
        const float* fr = &feat_s[n * FP + h * FDIM];
        const float* alh = al + h * FDIM;
        const float* arh = ar + h * FDIM;
        float a = 0.f, b = 0.f;
#pragma unroll 8
        for (int f = 0; f < FDIM; ++f) {
            float fv = fr[f];
            a = fmaf(fv, alh[f], a);
            b = fmaf(fv, arh[f], b);
        }
        el_s[n][h] = a;
        er_s[n][h] = b;
    }
    __syncthreads();

    // per-dst max over existing edges
    if (t < 2 * NPG) {
        int d = t >> 1, h = t & 1;
        float erd = er_s[d][h];
        float m = -3.4e38f;
        for (int s = 0; s < NPG; ++s) {
            if (cnt[d * AP + s] > 0) {
                float e = leaky(el_s[s][h] + erd, 0.2f);
                m = fmaxf(m, e);
            }
        }
        m_s[d][h] = m;
    }
    __syncthreads();

    // dense A build: A[h][d][s] = cnt * exp(e - m).  Plane 1 overwrites cnt
    // (each padded index touched by exactly one thread, read-before-write).
    for (int p = t; p < NPG * AP; p += 256) {
        int d = p / AP, s = p - d * AP;
        int c = cnt[p];
        float x0 = 0.f, x1 = 0.f;
        if (c > 0) {
            float fc = (float)c;
            x0 = fc * __expf(leaky(el_s[s][0] + er_s[d][0], 0.2f) - m_s[d][0]);
            x1 = fc * __expf(leaky(el_s[s][1] + er_s[d][1], 0.2f) - m_s[d][1]);
        }
        A_s[p] = x0;
        A_s[NPG * AP + p] = x1;
    }
    __syncthreads();

    // denominators -> reciprocals
    if (t < 2 * NPG) {
        int d = t >> 1, h = t & 1;
        const float* Ar = &A_s[h * NPG * AP + d * AP];
        float sum = 0.f;
        for (int s = 0; s < NPG; ++s) sum += Ar[s];
        rden_s[d][h] = 1.0f / sum;
    }
    __syncthreads();

    // ---- aggregation: rst[d][j] = sum_s A[h][d][s] * feat[s][j] ----
    float agg[25];
#pragma unroll
    for (int i = 0; i < 25; ++i) agg[i] = 0.f;
    const int hh = j >> 6;
    const float* Ah = &A_s[hh * NPG * AP];
    for (int sb = 0; sb < 48; sb += 4) {
        float fv0 = feat_s[(sb + 0) * FP + j];
        float fv1 = feat_s[(sb + 1) * FP + j];
        float fv2 = feat_s[(sb + 2) * FP + j];
        float fv3 = feat_s[(sb + 3) * FP + j];
#pragma unroll
        for (int i = 0; i < 25; ++i) {
            float4 a4 = *(const float4*)&Ah[(n0 + i) * AP + sb];
            float v = agg[i];
            v = fmaf(a4.x, fv0, v);
            v = fmaf(a4.y, fv1, v);
            v = fmaf(a4.z, fv2, v);
            v = fmaf(a4.w, fv3, v);
            agg[i] = v;
        }
    }
    {
        float fv0 = feat_s[48 * FP + j];
        float fv1 = feat_s[49 * FP + j];
#pragma unroll
        for (int i = 0; i < 25; ++i) {
            float4 a4 = *(const float4*)&Ah[(n0 + i) * AP + 48];  // .z/.w are zero pad
            agg[i] = fmaf(a4.x, fv0, fmaf(a4.y, fv1, agg[i]));
        }
    }
    // normalize by denom + residual
#pragma unroll
    for (int i = 0; i < 25; ++i) {
        int d = n0 + i;
        float resid;
        if constexpr (RESW) resid = accR[i];
        else resid = h_s[d * K + j];
        agg[i] = resid + agg[i] * rden_s[d][hh];
    }
    __syncthreads();                      // all feat_s readers done
#pragma unroll
    for (int i = 0; i < 25; ++i) feat_s[(n0 + i) * FP + j] = agg[i];  // pre-norm rst
    __syncthreads();

    // LayerNorm stats: one wave per row, butterfly reduce
    {
        int wv = t >> 6, lane = t & 63;
        for (int n = wv; n < NPG; n += 4) {
            float v0 = feat_s[n * FP + lane];
            float v1 = feat_s[n * FP + 64 + lane];
            float s = v0 + v1;
            float q = v0 * v0 + v1 * v1;
#pragma unroll
            for (int off = 32; off >= 1; off >>= 1) {
                s += __shfl_xor(s, off, 64);
                q += __shfl_xor(q, off, 64);
            }
            if (lane == 0) {
                float mu = s * (1.f / HF);
                float var = q * (1.f / HF) - mu * mu;
                mu_s[n] = mu;
                rs_s[n] = rsqrtf(var + 1e-5f);
            }
        }
    }
    __syncthreads();

    // normalize + affine + leaky; write h_next; accumulate readout partials
    const float gq = gw[j], bq = bw[j];
    float part = 0.f;
#pragma unroll
    for (int i = 0; i < 25; ++i) {
        int d = n0 + i;
        float y = (agg[i] - mu_s[d]) * rs_s[d] * gq + bq;
        y = leaky(y, 0.1f);
        if constexpr (WRITE_H) hout[(size_t)(nbase + d) * HF + j] = y;
        part += y;
    }
    psum[grp][j] = part;
    __syncthreads();
    if (t < FDIM) {
        float s = (psum[0][t] + psum[0][t + 64] + psum[1][t] + psum[1][t + 64]) * (1.f / (2 * NPG));
        out[(size_t)g * (3 * FDIM) + layer * FDIM + t] = leaky(s, 0.1f);
    }
}

extern "C" void kernel_launch(void* const* d_in, const int* in_sizes, int n_in,
                              void* d_out, int out_size, void* d_ws, size_t ws_size,
                              hipStream_t stream) {
    const float* x   = (const float*)d_in[0];
    const float* W0  = (const float*)d_in[1];
    const float* al0 = (const float*)d_in[2];
    const float* ar0 = (const float*)d_in[3];
    const float* rW0 = (const float*)d_in[4];
    const float* g0  = (const float*)d_in[5];
    const float* b0  = (const float*)d_in[6];
    const float* W1  = (const float*)d_in[7];
    const float* al1 = (const float*)d_in[8];
    const float* ar1 = (const float*)d_in[9];
    const float* g1  = (const float*)d_in[10];
    const float* b1  = (const float*)d_in[11];
    const float* W2  = (const float*)d_in[12];
    const float* al2 = (const float*)d_in[13];
    const float* ar2 = (const float*)d_in[14];
    const float* g2  = (const float*)d_in[15];
    const float* b2  = (const float*)d_in[16];
    const int* src   = (const int*)d_in[17];
    const int* dst   = (const int*)d_in[18];
    float* out = (float*)d_out;

    float* bufA = (float*)d_ws;                  // h1 [N,128]
    float* bufB = bufA + (size_t)NNODES * HF;    // h2 [N,128]

    layer_kernel<64, true, true><<<NGRAPH, 256, 0, stream>>>(
        x, W0, rW0, al0, ar0, g0, b0, src, dst, bufA, out, 0);
    layer_kernel<128, false, true><<<NGRAPH, 256, 0, stream>>>(
        bufA, W1, nullptr, al1, ar1, g1, b1, src, dst, bufB, out, 1);
    layer_kernel<128, false, false><<<NGRAPH, 256, 0, stream>>>(
        bufB, W2, nullptr, al2, ar2, g2, b2, src, dst, nullptr, out, 2);
}

// Round 3
// 368.115 us; speedup vs baseline: 2.1104x; 1.7380x over previous
//
#include <hip/hip_runtime.h>

#define NPG    50
#define HF     128
#define FDIM   64
#define NGRAPH 2048
#define NNODES 102400
#define EPG    400
#define SP     72          // featT / P row stride (bf16 elems)
#define PPLANE (64 * SP)   // one head's P plane
#define CS     52          // cnt row stride (ints)
#define RSTP   132         // rst/res fp32 row stride

typedef __attribute__((ext_vector_type(8))) short bf16x8;
typedef __attribute__((ext_vector_type(4))) float floatx4;

__device__ __forceinline__ float leaky(float x, float s) { return x >= 0.f ? x : x * s; }
__device__ __forceinline__ unsigned short f2bf(float f) {   // RNE fp32->bf16
    unsigned u = __float_as_uint(f);
    return (unsigned short)((u + 0x7fffu + ((u >> 16) & 1u)) >> 16);
}
__device__ __forceinline__ float bf2f(unsigned short h) {
    return __uint_as_float(((unsigned)h) << 16);
}

// Build transposed bf16 weights: wt0cat[256][64] = [W0|resW0]^T, wt1/wt2[128][128] = W^T
__global__ void prep_w(const float* __restrict__ W0, const float* __restrict__ rW0,
                       const float* __restrict__ W1, const float* __restrict__ W2,
                       unsigned short* __restrict__ wt0, unsigned short* __restrict__ wt1,
                       unsigned short* __restrict__ wt2) {
    int i = blockIdx.x * 256 + threadIdx.x;
    if (i < 256 * 64) {
        int n = i >> 6, k = i & 63;
        float v = (n < 128) ? W0[k * 128 + n] : rW0[k * 128 + (n - 128)];
        wt0[i] = f2bf(v);
    }
    if (i < 128 * 128) {
        int n = i >> 7, k = i & 127;
        wt1[i] = f2bf(W1[k * 128 + n]);
        wt2[i] = f2bf(W2[k * 128 + n]);
    }
}

// One block per graph, fully fused MFMA layer.
template <int K, bool RESW, bool WRITE_H>
__global__ __launch_bounds__(512, 4) void layer_kernel(
    const float* __restrict__ hin, const unsigned short* __restrict__ Wt,
    const float* __restrict__ al, const float* __restrict__ ar,
    const float* __restrict__ gw, const float* __restrict__ bw,
    const int* __restrict__ src, const int* __restrict__ dst,
    float* __restrict__ hout, float* __restrict__ out, int layer)
{
    __shared__ unsigned short featT[HF * SP];            // 18432 B, bf16 feat^T [col][s]
    __shared__ __align__(16) char uni[28832];            // P(18432)+cnt(10400) | rst(26400)
    __shared__ float res_s[RESW ? NPG * RSTP : 1];
    __shared__ float el_s[NPG * 2], er_s[NPG * 2], m_s[NPG * 2], rden_s[NPG * 2];
    __shared__ float mu_s[NPG], rs_s[NPG], psum[4 * HF];

    unsigned short* P = (unsigned short*)uni;            // [2][64][SP]
    int* cnt = (int*)(uni + 2 * PPLANE * 2);             // [50][CS]
    float* rst_s = (float*)uni;                          // [50][RSTP], aliases P+cnt

    const int g = blockIdx.x, t = threadIdx.x;
    const int nbase = g * NPG;
    const int w = t >> 6, lane = t & 63;
    const int quad = lane >> 4, l16 = lane & 15;

    // early edge loads (latency hidden behind zeroing + GEMM)
    int es = 0, ed = 0;
    if (t < EPG) {
        es = src[g * EPG + t] - nbase;
        ed = dst[g * EPG + t] - nbase;
    }

    // zero P + cnt
    for (int i = t; i < 28832 / 4; i += 512) ((int*)uni)[i] = 0;
    __syncthreads();

    if (t < EPG) atomicAdd(&cnt[ed * CS + es], 1);
    if (t < NPG) atomicAdd(&cnt[t * CS + t], 1);          // self loops

    // ---- GEMM via MFMA: feat[64xN] = h[64xK] @ W[KxN] ----
    constexpr int KS = K / 32;
    constexpr int NT = RESW ? 8 : 4;
    const int mt = w & 3;
    const int ntbase = (w >> 2) * NT;

    // A-fragments: lane holds A[m=l16][k=quad*8+j], row clamped to <NPG
    int mrow = mt * 16 + l16;
    if (mrow >= NPG) mrow = NPG - 1;
    const float* hrow = hin + (size_t)(nbase + mrow) * K;
    bf16x8 afr[KS];
#pragma unroll
    for (int ks = 0; ks < KS; ++ks) {
        int k0 = ks * 32 + quad * 8;
        float4 p0 = *(const float4*)(hrow + k0);
        float4 p1 = *(const float4*)(hrow + k0 + 4);
        bf16x8 a;
        a[0] = (short)f2bf(p0.x); a[1] = (short)f2bf(p0.y);
        a[2] = (short)f2bf(p0.z); a[3] = (short)f2bf(p0.w);
        a[4] = (short)f2bf(p1.x); a[5] = (short)f2bf(p1.y);
        a[6] = (short)f2bf(p1.z); a[7] = (short)f2bf(p1.w);
        afr[ks] = a;
    }

    floatx4 acc[NT];
    const floatx4 zf = {0.f, 0.f, 0.f, 0.f};
#pragma unroll
    for (int nt = 0; nt < NT; ++nt) acc[nt] = zf;
#pragma unroll
    for (int nt = 0; nt < NT; ++nt) {
        const unsigned short* wrow = Wt + (size_t)((ntbase + nt) * 16 + l16) * K;
#pragma unroll
        for (int ks = 0; ks < KS; ++ks) {
            bf16x8 b = *(const bf16x8*)(wrow + ks * 32 + quad * 8);
            acc[nt] = __builtin_amdgcn_mfma_f32_16x16x32_bf16(afr[ks], b, acc[nt], 0, 0, 0);
        }
    }
    // store: feat cols -> featT bf16 (transposed); res cols (layer0) -> res_s fp32
#pragma unroll
    for (int nt = 0; nt < NT; ++nt) {
        int n = (ntbase + nt) * 16 + l16;
#pragma unroll
        for (int r = 0; r < 4; ++r) {
            int d = mt * 16 + quad * 4 + r;   // C/D: row=quad*4+reg, col=l16
            if (!RESW || n < HF) {
                featT[n * SP + d] = f2bf(acc[nt][r]);
            } else if (d < NPG) {
                res_s[d * RSTP + (n - HF)] = acc[nt][r];
            }
        }
    }
    __syncthreads();

    // ---- el/er per (node, head) from bf16 featT ----
    if (t < 2 * NPG) {
        int n = t >> 1, h = t & 1;
        float a = 0.f, b = 0.f;
#pragma unroll 8
        for (int f = 0; f < FDIM; ++f) {
            float fv = bf2f(featT[(h * FDIM + f) * SP + n]);
            a = fmaf(fv, al[h * FDIM + f], a);
            b = fmaf(fv, ar[h * FDIM + f], b);
        }
        el_s[n * 2 + h] = a;
        er_s[n * 2 + h] = b;
    }
    __syncthreads();

    // per-dst max over existing edges
    if (t < 2 * NPG) {
        int d = t >> 1, h = t & 1;
        float erd = er_s[d * 2 + h];
        float m = -3.4e38f;
        for (int s = 0; s < NPG; ++s)
            if (cnt[d * CS + s] > 0)
                m = fmaxf(m, leaky(el_s[s * 2 + h] + erd, 0.2f));
        m_s[d * 2 + h] = m;
    }
    __syncthreads();

    // P fill (sparse entries only; rest stays zero)
    for (int i = t; i < NPG * NPG; i += 512) {
        int d = i / NPG, s = i - d * NPG;
        int c = cnt[d * CS + s];
        if (c > 0) {
            float fc = (float)c;
            float e0 = leaky(el_s[s * 2 + 0] + er_s[d * 2 + 0], 0.2f);
            float e1 = leaky(el_s[s * 2 + 1] + er_s[d * 2 + 1], 0.2f);
            P[d * SP + s]          = f2bf(fc * __expf(e0 - m_s[d * 2 + 0]));
            P[PPLANE + d * SP + s] = f2bf(fc * __expf(e1 - m_s[d * 2 + 1]));
        }
    }
    __syncthreads();

    // denominators from the bf16-rounded P (softmax sums to exactly 1)
    if (t < 2 * NPG) {
        int d = t >> 1, h = t & 1;
        const unsigned short* Pr = P + h * PPLANE + d * SP;
        float ssum = 0.f;
        for (int s = 0; s < NPG; ++s) ssum += bf2f(Pr[s]);
        rden_s[d * 2 + h] = 1.0f / ssum;
    }
    __syncthreads();

    // ---- aggregation via MFMA: rst[64x64 per head] = P[64x64] @ feat[64x64] ----
    const int hd = w >> 2, amt = w & 3;
    const unsigned short* Ph = P + hd * PPLANE;
    bf16x8 ap[2];
#pragma unroll
    for (int ks = 0; ks < 2; ++ks)
        ap[ks] = *(const bf16x8*)(Ph + (amt * 16 + l16) * SP + ks * 32 + quad * 8);
    floatx4 ag[4];
#pragma unroll
    for (int nt = 0; nt < 4; ++nt) ag[nt] = zf;
#pragma unroll
    for (int nt = 0; nt < 4; ++nt) {
        const unsigned short* fr = featT + (size_t)(hd * 64 + nt * 16 + l16) * SP;
#pragma unroll
        for (int ks = 0; ks < 2; ++ks) {
            bf16x8 b = *(const bf16x8*)(fr + ks * 32 + quad * 8);
            ag[nt] = __builtin_amdgcn_mfma_f32_16x16x32_bf16(ap[ks], b, ag[nt], 0, 0, 0);
        }
    }

    // scale by 1/denom + residual (still in registers, P region still live)
    float v[4][4];
#pragma unroll
    for (int nt = 0; nt < 4; ++nt) {
#pragma unroll
        for (int r = 0; r < 4; ++r) {
            int d = amt * 16 + quad * 4 + r;
            int dc = d < NPG ? d : NPG - 1;
            int c = hd * 64 + nt * 16 + l16;
            float resid = RESW ? res_s[dc * RSTP + c]
                               : hin[(size_t)(nbase + dc) * K + c];
            v[nt][r] = ag[nt][r] * rden_s[dc * 2 + hd] + resid;
        }
    }
    __syncthreads();   // all P/cnt readers done; rst_s may overwrite
#pragma unroll
    for (int nt = 0; nt < 4; ++nt) {
#pragma unroll
        for (int r = 0; r < 4; ++r) {
            int d = amt * 16 + quad * 4 + r;
            if (d < NPG) rst_s[d * RSTP + hd * 64 + nt * 16 + l16] = v[nt][r];
        }
    }
    __syncthreads();

    // LayerNorm stats: one wave per row
    for (int n = w; n < NPG; n += 8) {
        float v0 = rst_s[n * RSTP + lane];
        float v1 = rst_s[n * RSTP + 64 + lane];
        float s = v0 + v1, q = v0 * v0 + v1 * v1;
#pragma unroll
        for (int off = 32; off >= 1; off >>= 1) {
            s += __shfl_xor(s, off, 64);
            q += __shfl_xor(q, off, 64);
        }
        if (lane == 0) {
            float mu = s * (1.f / HF);
            mu_s[n] = mu;
            rs_s[n] = rsqrtf(q * (1.f / HF) - mu * mu + 1e-5f);
        }
    }
    __syncthreads();

    // normalize + affine + leaky; write h_next; readout partials
    const int c = t & 127, grp = t >> 7;
    const float gq = gw[c], bq = bw[c];
    float part = 0.f;
    for (int n = grp; n < NPG; n += 4) {
        float y = (rst_s[n * RSTP + c] - mu_s[n]) * rs_s[n] * gq + bq;
        y = leaky(y, 0.1f);
        if (WRITE_H) hout[(size_t)(nbase + n) * HF + c] = y;
        part += y;
    }
    psum[grp * HF + c] = part;
    __syncthreads();
    if (t < FDIM) {
        float s = 0.f;
#pragma unroll
        for (int g2 = 0; g2 < 4; ++g2)
            s += psum[g2 * HF + t] + psum[g2 * HF + t + FDIM];
        out[(size_t)g * (3 * FDIM) + layer * FDIM + t] = leaky(s * (1.f / (2 * NPG)), 0.1f);
    }
}

extern "C" void kernel_launch(void* const* d_in, const int* in_sizes, int n_in,
                              void* d_out, int out_size, void* d_ws, size_t ws_size,
                              hipStream_t stream) {
    const float* x   = (const float*)d_in[0];
    const float* W0  = (const float*)d_in[1];
    const float* al0 = (const float*)d_in[2];
    const float* ar0 = (const float*)d_in[3];
    const float* rW0 = (const float*)d_in[4];
    const float* g0  = (const float*)d_in[5];
    const float* b0  = (const float*)d_in[6];
    const float* W1  = (const float*)d_in[7];
    const float* al1 = (const float*)d_in[8];
    const float* ar1 = (const float*)d_in[9];
    const float* g1  = (const float*)d_in[10];
    const float* b1  = (const float*)d_in[11];
    const float* W2  = (const float*)d_in[12];
    const float* al2 = (const float*)d_in[13];
    const float* ar2 = (const float*)d_in[14];
    const float* g2  = (const float*)d_in[15];
    const float* b2  = (const float*)d_in[16];
    const int* src   = (const int*)d_in[17];
    const int* dst   = (const int*)d_in[18];
    float* out = (float*)d_out;

    char* ws = (char*)d_ws;
    float* bufA = (float*)ws;                                   // h1 [N,128] fp32
    float* bufB = (float*)(ws + (size_t)NNODES * HF * 4);       // h2 [N,128] fp32
    unsigned short* wt0 = (unsigned short*)(ws + (size_t)2 * NNODES * HF * 4);
    unsigned short* wt1 = wt0 + 256 * 64;
    unsigned short* wt2 = wt1 + 128 * 128;

    prep_w<<<64, 256, 0, stream>>>(W0, rW0, W1, W2, wt0, wt1, wt2);

    layer_kernel<64, true, true><<<NGRAPH, 512, 0, stream>>>(
        x, wt0, al0, ar0, g0, b0, src, dst, bufA, out, 0);
    layer_kernel<128, false, true><<<NGRAPH, 512, 0, stream>>>(
        bufA, wt1, al1, ar1, g1, b1, src, dst, bufB, out, 1);
    layer_kernel<128, false, false><<<NGRAPH, 512, 0, stream>>>(
        bufB, wt2, al2, ar2, g2, b2, src, dst, nullptr, out, 2);
}

// Round 5
// 291.938 us; speedup vs baseline: 2.6611x; 1.2609x over previous
//
#include <hip/hip_runtime.h>

#define NPG    50
#define HF     128
#define FDIM   64
#define NGRAPH 2048
#define NNODES 102400
#define EPG    400
#define SP     72     // featT row stride (bf16): 144B, 16B-aligned
#define CS2    33     // cnt row stride (ints): odd -> conflict-free column gather
#define RSTP   129    // rst/res fp32 row stride (odd)

typedef __attribute__((ext_vector_type(8))) short bf16x8;
typedef __attribute__((ext_vector_type(4))) float floatx4;

__device__ __forceinline__ float leaky(float x, float s) { return x >= 0.f ? x : x * s; }
__device__ __forceinline__ unsigned short f2bf(float f) {   // RNE fp32->bf16
    unsigned u = __float_as_uint(f);
    return (unsigned short)((u + 0x7fffu + ((u >> 16) & 1u)) >> 16);
}
__device__ __forceinline__ float bf2f(unsigned short h) {
    return __uint_as_float(((unsigned)h) << 16);
}

// Build transposed bf16 weights: wt0[256][64] = [W0|resW0]^T, wt1/wt2[128][128] = W^T
__global__ void prep_w(const float* __restrict__ W0, const float* __restrict__ rW0,
                       const float* __restrict__ W1, const float* __restrict__ W2,
                       unsigned short* __restrict__ wt0, unsigned short* __restrict__ wt1,
                       unsigned short* __restrict__ wt2) {
    int i = blockIdx.x * 256 + threadIdx.x;
    if (i < 256 * 64) {
        int n = i >> 6, k = i & 63;
        float v = (n < 128) ? W0[k * 128 + n] : rW0[k * 128 + (n - 128)];
        wt0[i] = f2bf(v);
    }
    if (i < 128 * 128) {
        int n = i >> 7, k = i & 127;
        wt1[i] = f2bf(W1[k * 128 + n]);
        wt2[i] = f2bf(W2[k * 128 + n]);
    }
}

template <int K, bool RESW, bool WRITE_H>
__global__ __launch_bounds__(512, 6) void layer_kernel(
    const float* __restrict__ hin, const unsigned short* __restrict__ Wt,
    const float* __restrict__ al, const float* __restrict__ ar,
    const float* __restrict__ gw, const float* __restrict__ bw,
    const int* __restrict__ src, const int* __restrict__ dst,
    float* __restrict__ hout, float* __restrict__ out, int layer)
{
    __shared__ unsigned short featT[HF * SP];     // 18432 B  bf16 feat^T [col][node]
    __shared__ int cnt[NPG * CS2];                // 6600 B   2 counts packed per int
    __shared__ float rstres[NPG * RSTP];          // 25800 B  res (L0) then rst
    __shared__ float el_s[2 * 64], er_s[2 * 64];  // [head][node]
    __shared__ float rden_s[2 * 64];
    __shared__ float elmax_s[2];
    __shared__ float musum[64], sqsum[64];
    __shared__ float psum[HF];

    const int g = blockIdx.x, t = threadIdx.x;
    const int nbase = g * NPG;
    const int w = t >> 6, lane = t & 63, quad = lane >> 4, l16 = lane & 15;

    // early edge loads
    int es = 0, ed = 0;
    if (t < EPG) { es = src[g * EPG + t] - nbase; ed = dst[g * EPG + t] - nbase; }

    // ---- P0: zero ----
    for (int i = t; i < NPG * CS2; i += 512) cnt[i] = 0;
    if (t < 64) { musum[t] = 0.f; sqsum[t] = 0.f; }
    if (t < HF) psum[t] = 0.f;
    __syncthreads();

    if (t < EPG) atomicAdd(&cnt[ed * CS2 + (es >> 1)], 1 << ((es & 1) * 16));
    if (t < NPG) atomicAdd(&cnt[t * CS2 + (t >> 1)], 1 << ((t & 1) * 16));

    // ---- P1: GEMM via MFMA + el/er + featT/res stores ----
    constexpr int KS = K / 32;
    constexpr int NT = RESW ? 8 : 4;
    const int mt = w & 3;
    const int ntbase = (w >> 2) * NT;

    int mrow = mt * 16 + l16;
    if (mrow >= NPG) mrow = NPG - 1;
    const float* hrow = hin + (size_t)(nbase + mrow) * K;
    bf16x8 afr[KS];
#pragma unroll
    for (int ks = 0; ks < KS; ++ks) {
        int k0 = ks * 32 + quad * 8;
        float4 p0 = *(const float4*)(hrow + k0);
        float4 p1 = *(const float4*)(hrow + k0 + 4);
        bf16x8 a;
        a[0] = (short)f2bf(p0.x); a[1] = (short)f2bf(p0.y);
        a[2] = (short)f2bf(p0.z); a[3] = (short)f2bf(p0.w);
        a[4] = (short)f2bf(p1.x); a[5] = (short)f2bf(p1.y);
        a[6] = (short)f2bf(p1.z); a[7] = (short)f2bf(p1.w);
        afr[ks] = a;
    }

    floatx4 acc[NT];
    const floatx4 zf = {0.f, 0.f, 0.f, 0.f};
#pragma unroll
    for (int nt = 0; nt < NT; ++nt) acc[nt] = zf;
#pragma unroll
    for (int nt = 0; nt < NT; ++nt) {
        const unsigned short* wrow = Wt + (size_t)((ntbase + nt) * 16 + l16) * K;
#pragma unroll
        for (int ks = 0; ks < KS; ++ks) {
            bf16x8 b = *(const bf16x8*)(wrow + ks * 32 + quad * 8);
            acc[nt] = __builtin_amdgcn_mfma_f32_16x16x32_bf16(afr[ks], b, acc[nt], 0, 0, 0);
        }
    }

    // el/er partials from fp32 acc: butterfly over l16 lanes.
    // RESW (layer0): waves 0..3 hold cols 0..127 -> pe0 = head0 (nt<4), pe1 = head1.
    // !RESW: each wave holds one head's 64 cols (hd = w>>2) -> pe0 only.
    if (!RESW || w < 4) {
        float pe0[4] = {0,0,0,0}, pr0[4] = {0,0,0,0};
        float pe1[4] = {0,0,0,0}, pr1[4] = {0,0,0,0};
#pragma unroll
        for (int nt = 0; nt < NT; ++nt) {
            int col = (ntbase + nt) * 16 + l16;
            if (RESW && col >= HF) continue;
            float av = al[col], rv = ar[col];
            bool second = RESW && (nt >= 4);
#pragma unroll
            for (int r = 0; r < 4; ++r) {
                float x = acc[nt][r];
                if (second) { pe1[r] = fmaf(x, av, pe1[r]); pr1[r] = fmaf(x, rv, pr1[r]); }
                else        { pe0[r] = fmaf(x, av, pe0[r]); pr0[r] = fmaf(x, rv, pr0[r]); }
            }
        }
#pragma unroll
        for (int m = 1; m <= 8; m <<= 1) {
#pragma unroll
            for (int r = 0; r < 4; ++r) {
                pe0[r] += __shfl_xor(pe0[r], m, 64);
                pr0[r] += __shfl_xor(pr0[r], m, 64);
                if (RESW) { pe1[r] += __shfl_xor(pe1[r], m, 64);
                            pr1[r] += __shfl_xor(pr1[r], m, 64); }
            }
        }
        if (l16 == 0) {
#pragma unroll
            for (int r = 0; r < 4; ++r) {
                int row = mt * 16 + quad * 4 + r;
                if (RESW) {
                    el_s[row] = pe0[r];      er_s[row] = pr0[r];
                    el_s[64 + row] = pe1[r]; er_s[64 + row] = pr1[r];
                } else {
                    int hd = w >> 2;
                    el_s[hd * 64 + row] = pe0[r];
                    er_s[hd * 64 + row] = pr0[r];
                }
            }
        }
    }

    // featT stores (b64-packed) / res stores (L0 high cols)
#pragma unroll
    for (int nt = 0; nt < NT; ++nt) {
        int n = (ntbase + nt) * 16 + l16;
        if (!RESW || n < HF) {
            unsigned lo = (unsigned)f2bf(acc[nt][0]) | ((unsigned)f2bf(acc[nt][1]) << 16);
            unsigned hi = (unsigned)f2bf(acc[nt][2]) | ((unsigned)f2bf(acc[nt][3]) << 16);
            uint2 pk = {lo, hi};
            *(uint2*)&featT[n * SP + mt * 16 + quad * 4] = pk;
        } else {
#pragma unroll
            for (int r = 0; r < 4; ++r) {
                int d = mt * 16 + quad * 4 + r;
                if (d < NPG) rstres[d * RSTP + (n - HF)] = acc[nt][r];
            }
        }
    }
    __syncthreads();

    // ---- P2: elmax[h] (leaky is monotone: max_s leaky(el+er) = leaky(max el + er)) ----
    if (w < 2) {
        float v = (lane < NPG) ? el_s[w * 64 + lane] : -3.4e38f;
#pragma unroll
        for (int m = 32; m >= 1; m >>= 1) v = fmaxf(v, __shfl_xor(v, m, 64));
        if (lane == 0) elmax_s[w] = v;
    }
    __syncthreads();

    // ---- P3: A-frag exp build + aggregation MFMA + epilogue + LN partials ----
    const int hd = w >> 2, amt = w & 3;
    const int d = amt * 16 + l16;   // this lane's A-frag dst row

    // prefetch residual (layers 1/2) early
    float resid[4][4];
    if (!RESW) {
#pragma unroll
        for (int nt = 0; nt < 4; ++nt)
#pragma unroll
            for (int r = 0; r < 4; ++r) {
                int dd = amt * 16 + quad * 4 + r;
                if (dd >= NPG) dd = NPG - 1;
                resid[nt][r] = hin[(size_t)(nbase + dd) * K + hd * 64 + nt * 16 + l16];
            }
    }

    float erd = (d < NPG) ? er_s[hd * 64 + d] : 0.f;
    float md = leaky(elmax_s[hd] + erd, 0.2f);
    bf16x8 ap[2];
    float rowsum = 0.f;
#pragma unroll
    for (int ks = 0; ks < 2; ++ks) {
        bf16x8 a;
#pragma unroll
        for (int j = 0; j < 8; ++j) {
            int s = ks * 32 + quad * 8 + j;
            float x = 0.f;
            if (d < NPG && s < NPG) {
                int c = (cnt[d * CS2 + (s >> 1)] >> ((s & 1) * 16)) & 0xffff;
                if (c) x = (float)c * __expf(leaky(el_s[hd * 64 + s] + erd, 0.2f) - md);
            }
            unsigned short xb = f2bf(x);
            a[j] = (short)xb;
            rowsum += bf2f(xb);
        }
        ap[ks] = a;
    }
    rowsum += __shfl_xor(rowsum, 16, 64);
    rowsum += __shfl_xor(rowsum, 32, 64);
    if (quad == 0) rden_s[hd * 64 + d] = 1.f / fmaxf(rowsum, 1e-30f);

    floatx4 ag[4];
#pragma unroll
    for (int nt = 0; nt < 4; ++nt) ag[nt] = zf;
#pragma unroll
    for (int nt = 0; nt < 4; ++nt) {
        const unsigned short* fr = &featT[(hd * 64 + nt * 16 + l16) * SP];
#pragma unroll
        for (int ks = 0; ks < 2; ++ks) {
            bf16x8 b = *(const bf16x8*)(fr + ks * 32 + quad * 8);
            ag[nt] = __builtin_amdgcn_mfma_f32_16x16x32_bf16(ap[ks], b, ag[nt], 0, 0, 0);
        }
    }

    // epilogue: scale + residual; LN partial sums; rst stores
    float vals[4][4];
    float s1[4] = {0,0,0,0}, s2[4] = {0,0,0,0};
#pragma unroll
    for (int nt = 0; nt < 4; ++nt) {
#pragma unroll
        for (int r = 0; r < 4; ++r) {
            int dd = amt * 16 + quad * 4 + r;
            float rdv = rden_s[hd * 64 + (dd < 64 ? dd : 63)];
            float rv;
            if (RESW) rv = (dd < NPG) ? rstres[dd * RSTP + hd * 64 + nt * 16 + l16] : 0.f;
            else rv = resid[nt][r];
            float vv = ag[nt][r] * rdv + rv;
            vals[nt][r] = vv;
            s1[r] += vv;
            s2[r] = fmaf(vv, vv, s2[r]);
        }
    }
#pragma unroll
    for (int m = 1; m <= 8; m <<= 1) {
#pragma unroll
        for (int r = 0; r < 4; ++r) {
            s1[r] += __shfl_xor(s1[r], m, 64);
            s2[r] += __shfl_xor(s2[r], m, 64);
        }
    }
    if (l16 == 0) {
#pragma unroll
        for (int r = 0; r < 4; ++r) {
            int dd = amt * 16 + quad * 4 + r;
            if (dd < NPG) { atomicAdd(&musum[dd], s1[r]); atomicAdd(&sqsum[dd], s2[r]); }
        }
    }
#pragma unroll
    for (int nt = 0; nt < 4; ++nt)
#pragma unroll
        for (int r = 0; r < 4; ++r) {
            int dd = amt * 16 + quad * 4 + r;
            if (dd < NPG) rstres[dd * RSTP + hd * 64 + nt * 16 + l16] = vals[nt][r];
        }
    __syncthreads();

    // ---- P4: normalize + affine + leaky + h write + readout partials ----
    const int c = t & 127, g4 = t >> 7;
    const float gq = gw[c], bq = bw[c];
    float part = 0.f;
    for (int n = g4; n < NPG; n += 4) {
        float mu = musum[n] * (1.f / HF);
        float rs = rsqrtf(sqsum[n] * (1.f / HF) - mu * mu + 1e-5f);
        float y = (rstres[n * RSTP + c] - mu) * rs * gq + bq;
        y = leaky(y, 0.1f);
        if (WRITE_H) hout[(size_t)(nbase + n) * HF + c] = y;
        part += y;
    }
    atomicAdd(&psum[c], part);
    __syncthreads();

    if (t < FDIM) {
        float s = (psum[t] + psum[t + FDIM]) * (1.f / (2 * NPG));
        out[(size_t)g * (3 * FDIM) + layer * FDIM + t] = leaky(s, 0.1f);
    }
}

extern "C" void kernel_launch(void* const* d_in, const int* in_sizes, int n_in,
                              void* d_out, int out_size, void* d_ws, size_t ws_size,
                              hipStream_t stream) {
    const float* x   = (const float*)d_in[0];
    const float* W0  = (const float*)d_in[1];
    const float* al0 = (const float*)d_in[2];
    const float* ar0 = (const float*)d_in[3];
    const float* rW0 = (const float*)d_in[4];
    const float* g0  = (const float*)d_in[5];
    const float* b0  = (const float*)d_in[6];
    const float* W1  = (const float*)d_in[7];
    const float* al1 = (const float*)d_in[8];
    const float* ar1 = (const float*)d_in[9];
    const float* g1  = (const float*)d_in[10];
    const float* b1  = (const float*)d_in[11];
    const float* W2  = (const float*)d_in[12];
    const float* al2 = (const float*)d_in[13];
    const float* ar2 = (const float*)d_in[14];
    const float* g2  = (const float*)d_in[15];
    const float* b2  = (const float*)d_in[16];
    const int* src   = (const int*)d_in[17];
    const int* dst   = (const int*)d_in[18];
    float* out = (float*)d_out;

    char* ws = (char*)d_ws;
    float* bufA = (float*)ws;                                   // h1 [N,128] fp32
    float* bufB = (float*)(ws + (size_t)NNODES * HF * 4);       // h2 [N,128] fp32
    unsigned short* wt0 = (unsigned short*)(ws + (size_t)2 * NNODES * HF * 4);
    unsigned short* wt1 = wt0 + 256 * 64;
    unsigned short* wt2 = wt1 + 128 * 128;

    prep_w<<<64, 256, 0, stream>>>(W0, rW0, W1, W2, wt0, wt1, wt2);

    layer_kernel<64, true, true><<<NGRAPH, 512, 0, stream>>>(
        x, wt0, al0, ar0, g0, b0, src, dst, bufA, out, 0);
    layer_kernel<128, false, true><<<NGRAPH, 512, 0, stream>>>(
        bufA, wt1, al1, ar1, g1, b1, src, dst, bufB, out, 1);
    layer_kernel<128, false, false><<<NGRAPH, 512, 0, stream>>>(
        bufB, wt2, al2, ar2, g2, b2, src, dst, nullptr, out, 2);
}